// Round 16
// baseline (668.671 us; speedup 1.0000x reference)
//
#include <hip/hip_runtime.h>
#include <stdint.h>

// ErnieImageAttention: hs(B,S,2048) -> QKV proj -> per-head RMSNorm -> RoPE ->
// full (non-causal) attention -> out proj + bias. B=2,S=4096,H=16,Hd=128.
// Round 16: r14's 8-phase 256^2 GEMM with the missing m201 depth: UNIFORM
// per-phase vmcnt(6) (3 half-tiles always in flight), prologue vmcnt(4),
// last-iter drain 4->2->0. Buffer/phase assignment identical to r14 (which
// passed correctness). Attention / qk_post / prep = r12/r15 verbatim.

#define S_LEN  4096
#define NHEAD  16
#define HDIM   128
#define DMODEL 2048
#define MROWS  8192          // B*S
#define NTK    (DMODEL/64)   // 32 K-tiles
#define NI     (NTK/2)       // 16 iterations (2 tiles each)

typedef unsigned short u16;
typedef unsigned int   u32;
typedef __attribute__((ext_vector_type(4)))  float  f32x4;
typedef __attribute__((ext_vector_type(16))) float  f32x16;
typedef __attribute__((ext_vector_type(4)))  u16    u16x4;
typedef __attribute__((ext_vector_type(8)))  u16    u16x8;
typedef __attribute__((ext_vector_type(4)))  u32    u32x4;
typedef __attribute__((ext_vector_type(8)))  __bf16 bf16x8;

__device__ __forceinline__ u16 f2bf(float x){          // RNE f32 -> bf16 bits
  unsigned u = __builtin_bit_cast(unsigned, x);
  u += 0x7FFFu + ((u >> 16) & 1u);
  return (u16)(u >> 16);
}
__device__ __forceinline__ float bf2f(u16 b){
  unsigned u = ((unsigned)b) << 16;
  return __builtin_bit_cast(float, u);
}
__device__ __forceinline__ u32 cvtpk(float lo, float hi_){ // [15:0]=bf16(lo) [31:16]=bf16(hi_)
  u32 r;
  asm("v_cvt_pk_bf16_f32 %0, %1, %2" : "=v"(r) : "v"(lo), "v"(hi_));
  return r;
}
// async global->LDS, 16B per lane; LDS dest must be wave-uniform base (+lane*16)
__device__ __forceinline__ void gload16(const void* g, void* l){
  __builtin_amdgcn_global_load_lds((__attribute__((address_space(1))) void*)g,
                                   (__attribute__((address_space(3))) void*)l,
                                   16, 0, 0);
}
// XCD-aware chunked swizzle (bijective when nwg % 8 == 0)
__device__ __forceinline__ int xcd_chunk(int bid, int nwg){
  return (bid & 7) * (nwg >> 3) + (bid >> 3);
}
__device__ __forceinline__ void vmwait(int vm){        // vm compile-time const
  if (vm == 6)      asm volatile("s_waitcnt vmcnt(6)" ::: "memory");
  else if (vm == 4) asm volatile("s_waitcnt vmcnt(4)" ::: "memory");
  else if (vm == 2) asm volatile("s_waitcnt vmcnt(2)" ::: "memory");
  else if (vm == 0) asm volatile("s_waitcnt vmcnt(0)" ::: "memory");
}

// ---------------- prep kernels ----------------
__global__ void k_cast_hs(const float* __restrict__ in, u16* __restrict__ out){
  size_t i = (size_t)blockIdx.x * 256 + threadIdx.x;   // 8 elems / thread
  const f32x4* p = (const f32x4*)in;
  f32x4 a = p[i*2], b = p[i*2+1];
  u16x8 o;
  o[0]=f2bf(a[0]); o[1]=f2bf(a[1]); o[2]=f2bf(a[2]); o[3]=f2bf(a[3]);
  o[4]=f2bf(b[0]); o[5]=f2bf(b[1]); o[6]=f2bf(b[2]); o[7]=f2bf(b[3]);
  ((u16x8*)out)[i] = o;
}

// fp32 [2048][2048] -> bf16 transposed [2048][2048] (out[n][k] = in[k][n])
__global__ void k_transpose_w(const float* __restrict__ in, u16* __restrict__ out){
  __shared__ float t[64][65];
  const int tid = threadIdx.x;
  const int k0 = blockIdx.x * 64, n0 = blockIdx.y * 64;
#pragma unroll
  for (int it = 0; it < 4; ++it){
    int slot = it*256 + tid;                 // 1024 float4 slots
    int r = slot >> 4, c = (slot & 15) * 4;
    f32x4 v = *(const f32x4*)&in[(size_t)(k0+r)*DMODEL + n0 + c];
    t[r][c] = v[0]; t[r][c+1] = v[1]; t[r][c+2] = v[2]; t[r][c+3] = v[3];
  }
  __syncthreads();
#pragma unroll
  for (int it = 0; it < 2; ++it){
    int slot = it*256 + tid;                 // 64 n-rows x 8 chunks
    int r = slot >> 3, c = (slot & 7) * 8;
    u16x8 o;
#pragma unroll
    for (int j = 0; j < 8; ++j) o[j] = f2bf(t[c+j][r]);
    *(u16x8*)&out[(size_t)(n0+r)*DMODEL + k0 + c] = o;
  }
}

__global__ void k_tables(const float* __restrict__ fr, float* __restrict__ cn,
                         float* __restrict__ sn){
  int i = blockIdx.x*256 + threadIdx.x;      // S*128 elements
  float f = fr[i];
  cn[i] = cosf(f); sn[i] = sinf(f);
}

// ================= 8-phase 256x256 GEMM (C = A * Bt^T, K = 2048) =================
// 8 waves (wr=wid>>2, wc=wid&3); per-wave output 128x64 = acc[8][4] 16x16
// fragments. LDS [2 buf][256][64] bf16 per operand, chunk-XOR swizzle.
// One half-tile (16KB, 2 gload16/thread) staged per phase; uniform vmcnt(6)
// keeps 3 halves in flight at every phase boundary (m201 depth).

// A half h = rows {64h..64h+63} u {128+64h..+63}
__device__ __forceinline__ void stage_Ah(const u16* __restrict__ A, int m0, int kt,
                                         int h, u16* dst, int lane, int wid){
#pragma unroll
  for (int r = 0; r < 2; ++r){
    int lr0 = r*64 + wid*8;                  // wave-uniform local-row base
    int rb  = (lr0 < 64) ? (h*64 + lr0) : (128 + h*64 + (lr0 - 64));
    int row = rb + (lane >> 3), cs = lane & 7, ci = cs ^ (row & 7);
    gload16(A + (size_t)(m0+row)*DMODEL + kt*64 + ci*8, dst + (size_t)rb*64);
  }
}
// B half h = rows U_{g=0..3} [g*64 + 32h, +32)
__device__ __forceinline__ void stage_Bh(const u16* __restrict__ Bt, int n0, int kt,
                                         int h, u16* dst, int lane, int wid){
#pragma unroll
  for (int r = 0; r < 2; ++r){
    int lr0 = r*64 + wid*8;
    int rb  = (lr0 >> 5)*64 + h*32 + (lr0 & 31);
    int row = rb + (lane >> 3), cs = lane & 7, ci = cs ^ (row & 7);
    gload16(Bt + (size_t)(n0+row)*DMODEL + kt*64 + ci*8, dst + (size_t)rb*64);
  }
}

struct Frags { bf16x8 af[4][2]; bf16x8 bv[2][2]; };

__device__ __forceinline__ void ld_frags(const u16* As, const u16* Bs, int mh, int nh,
                                         int lane, int wr, int wc, Frags& f){
#pragma unroll
  for (int mr = 0; mr < 4; ++mr){
    int row = wr*128 + mh*64 + mr*16 + (lane & 15);
    int sw = row & 7;
#pragma unroll
    for (int ks = 0; ks < 2; ++ks)
      f.af[mr][ks] = *(const bf16x8*)(As + (size_t)row*64 + (size_t)((ks*4 + (lane>>4)) ^ sw)*8);
  }
#pragma unroll
  for (int nr = 0; nr < 2; ++nr){
    int row = wc*64 + nh*32 + nr*16 + (lane & 15);
    int sw = row & 7;
#pragma unroll
    for (int ks = 0; ks < 2; ++ks)
      f.bv[nr][ks] = *(const bf16x8*)(Bs + (size_t)row*64 + (size_t)((ks*4 + (lane>>4)) ^ sw)*8);
  }
}

// barrier1 -> 16 MFMA (one quadrant) -> vmcnt(vm) -> barrier2
__device__ __forceinline__ void do_mfma(Frags& f, f32x4 (&acc)[8][4], int mh, int nh, int vm){
  asm volatile("" ::: "memory");
  __builtin_amdgcn_s_barrier();              // barrier1: publish, pace waves
  asm volatile("" ::: "memory");
  __builtin_amdgcn_s_setprio(1);
#pragma unroll
  for (int mr = 0; mr < 4; ++mr)
#pragma unroll
    for (int nr = 0; nr < 2; ++nr)
#pragma unroll
      for (int ks = 0; ks < 2; ++ks)
        acc[mh*4+mr][nh*2+nr] = __builtin_amdgcn_mfma_f32_16x16x32_bf16(
            f.af[mr][ks], f.bv[nr][ks], acc[mh*4+mr][nh*2+nr], 0, 0, 0);
  __builtin_amdgcn_s_setprio(0);
  vmwait(vm);                                // retire the half the NEXT phase reads
  __builtin_amdgcn_sched_barrier(0);         // pin MFMAs (+wait) above barrier2
  asm volatile("" ::: "memory");
  __builtin_amdgcn_s_barrier();              // barrier2: reads retired
  asm volatile("" ::: "memory");
}

__device__ __forceinline__ void gemm8p(const u16* __restrict__ A, const u16* __restrict__ Bt,
                                       int m0, int n0,
                                       u16 (*Asm)[256*64], u16 (*Bsm)[256*64],
                                       f32x4 (&acc)[8][4], int lane, int wid){
  const int wr = wid >> 2, wc = wid & 3;
  // prologue: tile0 (4 halves) + B-n0 of tile1; keep youngest 2 halves in flight
  stage_Ah(A,  m0, 0, 0, Asm[0], lane, wid);
  stage_Ah(A,  m0, 0, 1, Asm[0], lane, wid);
  stage_Bh(Bt, n0, 0, 0, Bsm[0], lane, wid);
  stage_Bh(Bt, n0, 0, 1, Bsm[0], lane, wid);
  stage_Bh(Bt, n0, 1, 0, Bsm[1], lane, wid);
  asm volatile("s_waitcnt vmcnt(4)" ::: "memory");   // Am0(0),Am1(0),Bn0(0) landed
  __builtin_amdgcn_s_barrier();
  asm volatile("" ::: "memory");

  Frags f;
#pragma unroll 1
  for (int I = 0; I < NI; ++I){
    const int t = 2*I;
    const bool last = (I == NI-1);
    // ---- phases 0-3: compute tile t (buf0) ----
    ld_frags(Asm[0], Bsm[0], 0, 0, lane, wr, wc, f);           // ph0: q(m0,n0)
    stage_Ah(A,  m0, t+1, 0, Asm[1], lane, wid);               //   A-m0(t+1)
    do_mfma(f, acc, 0, 0, 6);
    ld_frags(Asm[0], Bsm[0], 1, 0, lane, wr, wc, f);           // ph1: q(m1,n0)
    stage_Ah(A,  m0, t+1, 1, Asm[1], lane, wid);               //   A-m1(t+1)
    do_mfma(f, acc, 1, 0, 6);
    ld_frags(Asm[0], Bsm[0], 0, 1, lane, wr, wc, f);           // ph2: q(m0,n1)
    stage_Bh(Bt, n0, t+1, 1, Bsm[1], lane, wid);               //   B-n1(t+1)
    do_mfma(f, acc, 0, 1, 6);
    ld_frags(Asm[0], Bsm[0], 1, 1, lane, wr, wc, f);           // ph3: q(m1,n1)
    if (!last) stage_Bh(Bt, n0, t+2, 0, Bsm[0], lane, wid);    //   B-n0(t+2)
    do_mfma(f, acc, 1, 1, last ? 4 : 6);
    // ---- phases 4-7: compute tile t+1 (buf1) ----
    ld_frags(Asm[1], Bsm[1], 0, 0, lane, wr, wc, f);           // ph4
    if (!last) stage_Ah(A,  m0, t+2, 0, Asm[0], lane, wid);    //   A-m0(t+2)
    do_mfma(f, acc, 0, 0, last ? 2 : 6);
    ld_frags(Asm[1], Bsm[1], 1, 0, lane, wr, wc, f);           // ph5
    if (!last) stage_Ah(A,  m0, t+2, 1, Asm[0], lane, wid);    //   A-m1(t+2)
    do_mfma(f, acc, 1, 0, last ? 0 : 6);
    ld_frags(Asm[1], Bsm[1], 0, 1, lane, wr, wc, f);           // ph6
    if (!last) stage_Bh(Bt, n0, t+2, 1, Bsm[0], lane, wid);    //   B-n1(t+2)
    do_mfma(f, acc, 0, 1, last ? -1 : 6);
    ld_frags(Asm[1], Bsm[1], 1, 1, lane, wr, wc, f);           // ph7
    if (!last) stage_Bh(Bt, n0, t+3, 0, Bsm[1], lane, wid);    //   B-n0(t+3)
    do_mfma(f, acc, 1, 1, last ? -1 : 6);
  }
}

// QKV projection GEMM (256^2 tiles). N=6144 = [q|k|v], no block straddles.
__global__ __launch_bounds__(512, 2)
void k_gemm_qkv(const u16* __restrict__ A, const u16* __restrict__ Bt,
                u16* __restrict__ qkp, u16* __restrict__ vt){
  __shared__ u16 Asm[2][256*64];
  __shared__ u16 Bsm[2][256*64];
  const int lane = threadIdx.x & 63, wid = threadIdx.x >> 6;
  const int t  = xcd_chunk(blockIdx.x, 32*24);
  const int m0 = (t & 31) * 256;
  const int n0 = (t >> 5) * 256;
  f32x4 acc[8][4] = {};
  gemm8p(A, Bt, m0, n0, Asm, Bsm, acc, lane, wid);
  const int wr = wid >> 2, wc = wid & 3;
  if (n0 < 2*DMODEL){
#pragma unroll
    for (int mg = 0; mg < 8; ++mg)
#pragma unroll
      for (int ng = 0; ng < 4; ++ng){
        int col = n0 + wc*64 + ng*16 + (lane & 15);
#pragma unroll
        for (int r = 0; r < 4; ++r){
          int row = m0 + wr*128 + mg*16 + (lane >> 4)*4 + r;
          qkp[(size_t)row*4096 + col] = f2bf(acc[mg][ng][r]);
        }
      }
  } else {
    const int b = m0 >> 12;
#pragma unroll
    for (int mg = 0; mg < 8; ++mg)
#pragma unroll
      for (int ng = 0; ng < 4; ++ng){
        int ncol = n0 + wc*64 + ng*16 + (lane & 15);
        int hh = (ncol >> 7) & 15;
        int d  = ncol & 127;
        u16x4 pk;
#pragma unroll
        for (int r = 0; r < 4; ++r) pk[r] = f2bf(acc[mg][ng][r]);
        int s_ = (m0 & (S_LEN-1)) + wr*128 + mg*16 + (lane >> 4)*4;
        *(u16x4*)&vt[(((size_t)b*NHEAD + hh)*HDIM + d)*S_LEN + s_] = pk;
      }
  }
}

// per-head RMSNorm + RoPE; Q scaled by log2e/sqrt(128); layout [b][h][s][d]
__global__ __launch_bounds__(256)
void k_qk_post(const u16* __restrict__ qkp, const float* __restrict__ cn,
               const float* __restrict__ sn, const float* __restrict__ wqn,
               const float* __restrict__ wkn, u16* __restrict__ Qo, u16* __restrict__ Ko){
  const int lane = threadIdx.x & 63, wid = threadIdx.x >> 6;
  const int gw = blockIdx.x*4 + wid;     // (b*S+s)*16 + h
  const int row = gw >> 4;
  const int h  = gw & 15;
  const int s_ = row & (S_LEN-1);
  const int b  = row >> 12;
  const float c1 = cn[s_*HDIM + lane],      c2 = cn[s_*HDIM + 64 + lane];
  const float t1 = sn[s_*HDIM + lane],      t2 = sn[s_*HDIM + 64 + lane];
  const size_t ob = (((size_t)b*NHEAD + h)*S_LEN + s_)*HDIM;
  {
    const u16* p = qkp + (size_t)row*4096 + h*HDIM;
    float x1 = bf2f(p[lane]), x2 = bf2f(p[lane+64]);
    float ss = x1*x1 + x2*x2;
#pragma unroll
    for (int m = 1; m < 64; m <<= 1) ss += __shfl_xor(ss, m);
    float rn = rsqrtf(ss*(1.0f/128.0f) + 1e-5f);
    x1 *= rn * wqn[lane]; x2 *= rn * wqn[lane+64];
    const float qs = 0.12751743f;          // log2(e)/sqrt(128), folded softmax scale
    Qo[ob + lane]      = f2bf((x1*c1 - x2*t1) * qs);
    Qo[ob + 64 + lane] = f2bf((x2*c2 + x1*t2) * qs);
  }
  {
    const u16* p = qkp + (size_t)row*4096 + 2048 + h*HDIM;
    float x1 = bf2f(p[lane]), x2 = bf2f(p[lane+64]);
    float ss = x1*x1 + x2*x2;
#pragma unroll
    for (int m = 1; m < 64; m <<= 1) ss += __shfl_xor(ss, m);
    float rn = rsqrtf(ss*(1.0f/128.0f) + 1e-5f);
    x1 *= rn * wkn[lane]; x2 *= rn * wkn[lane+64];
    Ko[ob + lane]      = f2bf(x1*c1 - x2*t1);
    Ko[ob + 64 + lane] = f2bf(x2*c2 + x1*t2);
  }
}

// ---------------- attention: swapped-QK^T 32x32, in-register softmax ----------------
// (round-12/15 kernel verbatim — validated 4x)
__device__ __forceinline__ void stage_kv(const u16* __restrict__ Kg,
                                         const u16* __restrict__ Vt,
                                         size_t base, int kb,
                                         u16* Ksm, u16* Vsm, int lane, int wid){
#pragma unroll
  for (int it = 0; it < 4; ++it){
    int slot = it*256 + wid*64 + lane;       // 1024 chunks per tile
    { int row = slot >> 4, cs = slot & 15, ci = cs ^ (row & 7);
      gload16(Kg + base + (size_t)(kb*64 + row)*HDIM + ci*8, Ksm + (size_t)(it*256 + wid*64)*8); }
    { int row = slot >> 3, cs = slot & 7,  ci = cs ^ (row & 7);
      gload16(Vt + base + (size_t)row*S_LEN + kb*64 + ci*8,  Vsm + (size_t)(it*256 + wid*64)*8); }
  }
}

__global__ __launch_bounds__(256, 2)
void k_attn(const u16* __restrict__ Q, const u16* __restrict__ Kg,
            const u16* __restrict__ Vt, u16* __restrict__ Og){
  __shared__ u16 Ksm[2][64*128];           // [key][d], 16 chunks/row, ci = cs^(row&7)
  __shared__ u16 Vsm[2][128*64];           // [d][key],  8 chunks/row, ci = cs^(row&7)
  const int lane = threadIdx.x & 63, wid = threadIdx.x >> 6;
  const int col = lane & 31, hi = lane >> 5;
  const int t  = xcd_chunk(blockIdx.x, 1024);    // each XCD: 4 bh -> K/V L2-resident
  const int bh = t >> 5;
  const int q0 = (t & 31) * 128;
  const int b = bh >> 4, h = bh & 15;
  const size_t base = (size_t)bh * S_LEN * HDIM;
  const int qw = q0 + wid*32;

  stage_kv(Kg, Vt, base, 0, Ksm[0], Vsm[0], lane, wid);   // prologue: tile 0 (8 ops)

  bf16x8 qb[8];
  {
    const u16* qp = Q + base + (size_t)(qw + col)*HDIM + hi*8;
#pragma unroll
    for (int ks = 0; ks < 8; ++ks) qb[ks] = *(const bf16x8*)(qp + ks*16);
  }
  f32x16 acc[4] = {};                      // O[q=crow(r,hi)][d=dt*32+col]
  float lsum = 0.f;
  int cur = 0;

#pragma unroll 1
  for (int kb = 0; kb < S_LEN/64; ++kb){
    if (kb + 1 < S_LEN/64){
      stage_kv(Kg, Vt, base, kb + 1, Ksm[cur ^ 1], Vsm[cur ^ 1], lane, wid);
      asm volatile("s_waitcnt vmcnt(8)" ::: "memory");
    } else {
      asm volatile("s_waitcnt vmcnt(0)" ::: "memory");
    }
    __builtin_amdgcn_s_barrier();
    asm volatile("" ::: "memory");
    const u16* Ks = Ksm[cur];
    const u16* Vs = Vsm[cur];

    f32x16 s0 = {}, s1 = {};
    __builtin_amdgcn_s_setprio(1);
#pragma unroll
    for (int ks = 0; ks < 8; ++ks){
      int slot = (ks*2 + hi);
      int r0 = col;
      bf16x8 kf0 = *(const bf16x8*)(Ks + (size_t)r0*128 + (size_t)(slot ^ (r0 & 7))*8);
      s0 = __builtin_amdgcn_mfma_f32_32x32x16_bf16(kf0, qb[ks], s0, 0, 0, 0);
      int r1 = col + 32;
      bf16x8 kf1 = *(const bf16x8*)(Ks + (size_t)r1*128 + (size_t)(slot ^ (r1 & 7))*8);
      s1 = __builtin_amdgcn_mfma_f32_32x32x16_bf16(kf1, qb[ks], s1, 0, 0, 0);
    }
    __builtin_amdgcn_s_setprio(0);

    float p0[16], p1[16];
#pragma unroll
    for (int r = 0; r < 16; ++r){
      p0[r] = __builtin_amdgcn_exp2f(s0[r]);
      p1[r] = __builtin_amdgcn_exp2f(s1[r]);
      lsum += p0[r] + p1[r];
    }
    u32 cw0[8], cw1[8];
#pragma unroll
    for (int j = 0; j < 8; ++j){
      cw0[j] = cvtpk(p0[2*j], p0[2*j+1]);
      cw1[j] = cvtpk(p1[2*j], p1[2*j+1]);
    }
    bf16x8 pa[4];
#pragma unroll
    for (int ks = 0; ks < 4; ++ks){
      const u32* cw = (ks < 2) ? cw0 : cw1;
      const int c4 = (ks & 1) * 4;
      u32 n0 = hi ? cw[c4+2] : cw[c4+0];
      u32 n1 = hi ? cw[c4+3] : cw[c4+1];
      u32 s0w = hi ? cw[c4+0] : cw[c4+2];
      u32 s1w = hi ? cw[c4+1] : cw[c4+3];
      u32 f0 = __shfl_xor((int)s0w, 32);
      u32 f1 = __shfl_xor((int)s1w, 32);
      u32x4 w;
      w[0] = hi ? f0 : n0;
      w[1] = hi ? f1 : n1;
      w[2] = hi ? n0 : f0;
      w[3] = hi ? n1 : f1;
      pa[ks] = __builtin_bit_cast(bf16x8, w);
    }

    __builtin_amdgcn_s_setprio(1);
#pragma unroll
    for (int dt = 0; dt < 4; ++dt){
      int row = dt*32 + col;
      const u16* vb = Vs + (size_t)row*64;
      int sw = row & 7;
#pragma unroll
      for (int ks = 0; ks < 4; ++ks){
        bf16x8 vf = *(const bf16x8*)(vb + (size_t)((ks*2 + hi) ^ sw)*8);
        acc[dt] = __builtin_amdgcn_mfma_f32_32x32x16_bf16(pa[ks], vf, acc[dt], 0, 0, 0);
      }
    }
    __builtin_amdgcn_s_setprio(0);
    __builtin_amdgcn_s_barrier();
    asm volatile("" ::: "memory");
    cur ^= 1;
  }

  float tot = lsum + __shfl_xor(lsum, 32);
  float inv[16];
#pragma unroll
  for (int r = 0; r < 16; ++r){
    int qr = (r & 3) + 4*hi + 8*(r >> 2);
    inv[r] = 1.0f / __shfl(tot, qr);
  }
  const size_t orow0 = (size_t)b*S_LEN + q0 + wid*32;
#pragma unroll
  for (int dt = 0; dt < 4; ++dt){
    int d = h*HDIM + dt*32 + col;
#pragma unroll
    for (int r = 0; r < 16; ++r){
      int qr = (r & 3) + 4*hi + 8*(r >> 2);
      Og[(orow0 + qr)*DMODEL + d] = f2bf(acc[dt][r] * inv[r]);
    }
  }
}

// out = attn[8192][2048] @ w_out + b_out  (fp32 out), 256^2 8-phase
__global__ __launch_bounds__(512, 2)
void k_gemm_out(const u16* __restrict__ A, const u16* __restrict__ Bt,
                const float* __restrict__ bias, float* __restrict__ out){
  __shared__ u16 Asm[2][256*64];
  __shared__ u16 Bsm[2][256*64];
  const int lane = threadIdx.x & 63, wid = threadIdx.x >> 6;
  const int t  = xcd_chunk(blockIdx.x, 32*8);
  const int m0 = (t & 31) * 256;
  const int n0 = (t >> 5) * 256;
  f32x4 acc[8][4] = {};
  gemm8p(A, Bt, m0, n0, Asm, Bsm, acc, lane, wid);
  const int wr = wid >> 2, wc = wid & 3;
#pragma unroll
  for (int mg = 0; mg < 8; ++mg)
#pragma unroll
    for (int ng = 0; ng < 4; ++ng){
      int col = n0 + wc*64 + ng*16 + (lane & 15);
      float bv = bias[col];
#pragma unroll
      for (int r = 0; r < 4; ++r){
        int row = m0 + wr*128 + mg*16 + (lane >> 4)*4 + r;
        out[(size_t)row*DMODEL + col] = acc[mg][ng][r] + bv;
      }
    }
}

extern "C" void kernel_launch(void* const* d_in, const int* in_sizes, int n_in,
                              void* d_out, int out_size, void* d_ws, size_t ws_size,
                              hipStream_t stream){
  const float* hs    = (const float*)d_in[0];
  const float* freqs = (const float*)d_in[1];
  const float* wq    = (const float*)d_in[2];
  const float* wk    = (const float*)d_in[3];
  const float* wv    = (const float*)d_in[4];
  const float* nqw   = (const float*)d_in[5];
  const float* nkw   = (const float*)d_in[6];
  const float* wo    = (const float*)d_in[7];
  const float* bo    = (const float*)d_in[8];
  float* out = (float*)d_out;

  char* ws = (char*)d_ws;
  u16*   hs_bf = (u16*)(ws + 0);              // 33,554,432  (later reused as Q)
  u16*   wqkvT = (u16*)(ws + 33554432);       // 25,165,824
  u16*   woutT = (u16*)(ws + 58720256);       //  8,388,608
  float* cosn  = (float*)(ws + 67108864);     //  2,097,152
  float* sinn  = (float*)(ws + 69206016);     //  2,097,152
  u16*   qkp   = (u16*)(ws + 71303168);       // 67,108,864  (later reused as attn out)
  u16*   vt    = (u16*)(ws + 138412032);      // 33,554,432
  u16*   kbuf  = (u16*)(ws + 171966464);      // 33,554,432
  if (ws_size < 205520896ULL) return;         // need ~196 MiB of scratch
  u16* qbuf = hs_bf;                          // alias: hs dead after QKV GEMM
  u16* attn = qkp;                            // alias: qk-proj dead after qk_post

  k_cast_hs    <<<8192, 256, 0, stream>>>(hs, hs_bf);
  k_transpose_w<<<dim3(32,32), 256, 0, stream>>>(wq, wqkvT);
  k_transpose_w<<<dim3(32,32), 256, 0, stream>>>(wk, wqkvT + (size_t)DMODEL*DMODEL);
  k_transpose_w<<<dim3(32,32), 256, 0, stream>>>(wv, wqkvT + (size_t)2*DMODEL*DMODEL);
  k_transpose_w<<<dim3(32,32), 256, 0, stream>>>(wo, woutT);
  k_tables     <<<2048, 256, 0, stream>>>(freqs, cosn, sinn);
  k_gemm_qkv   <<<768, 512, 0, stream>>>(hs_bf, wqkvT, qkp, vt);
  k_qk_post    <<<32768, 256, 0, stream>>>(qkp, cosn, sinn, nqw, nkw, qbuf, kbuf);
  k_attn       <<<1024, 256, 0, stream>>>(qbuf, kbuf, vt, attn);
  k_gemm_out   <<<256, 512, 0, stream>>>(attn, woutT, bo, out);
}

// Round 17
// 638.265 us; speedup vs baseline: 1.0476x; 1.0476x over previous
//
#include <hip/hip_runtime.h>
#include <stdint.h>

// ErnieImageAttention: hs(B,S,2048) -> QKV proj -> per-head RMSNorm -> RoPE ->
// full (non-causal) attention -> out proj + bias. B=2,S=4096,H=16,Hd=128.
// FINAL (round 17) = round-12/15 composition, session best (642.5-646.3us).
// GEMMs: 16x16x32 MFMA, single 32KB LDS buffers, 2-barrier loop (3-4 blk/CU).
// Attention: swapped-QK^T 32x32, in-register softmax (cvt_pk + lane32 shuffle),
// counted-vmcnt K/V double-buffer, setprio, XCD-chunked block map.
// Abandoned after measurement: 8-phase 256^2 template (r14 vmcnt2 / r16 vmcnt6:
// correct but slower at K=2048, 1 blk/CU), retimed pipelines (r7/r10: raced),
// 32x32 GEMM core (r11: slower), 8-wave attn (r13: occupancy didn't rise).

#define S_LEN  4096
#define NHEAD  16
#define HDIM   128
#define DMODEL 2048
#define MROWS  8192          // B*S

typedef unsigned short u16;
typedef unsigned int   u32;
typedef __attribute__((ext_vector_type(4)))  float  f32x4;
typedef __attribute__((ext_vector_type(16))) float  f32x16;
typedef __attribute__((ext_vector_type(4)))  u16    u16x4;
typedef __attribute__((ext_vector_type(8)))  u16    u16x8;
typedef __attribute__((ext_vector_type(4)))  u32    u32x4;
typedef __attribute__((ext_vector_type(8)))  __bf16 bf16x8;

__device__ __forceinline__ u16 f2bf(float x){          // RNE f32 -> bf16 bits
  unsigned u = __builtin_bit_cast(unsigned, x);
  u += 0x7FFFu + ((u >> 16) & 1u);
  return (u16)(u >> 16);
}
__device__ __forceinline__ float bf2f(u16 b){
  unsigned u = ((unsigned)b) << 16;
  return __builtin_bit_cast(float, u);
}
__device__ __forceinline__ u32 cvtpk(float lo, float hi_){ // [15:0]=bf16(lo) [31:16]=bf16(hi_)
  u32 r;
  asm("v_cvt_pk_bf16_f32 %0, %1, %2" : "=v"(r) : "v"(lo), "v"(hi_));
  return r;
}
// async global->LDS, 16B per lane; LDS dest must be wave-uniform base (+lane*16)
__device__ __forceinline__ void gload16(const void* g, void* l){
  __builtin_amdgcn_global_load_lds((__attribute__((address_space(1))) void*)g,
                                   (__attribute__((address_space(3))) void*)l,
                                   16, 0, 0);
}
// XCD-aware chunked swizzle (bijective when nwg % 8 == 0)
__device__ __forceinline__ int xcd_chunk(int bid, int nwg){
  return (bid & 7) * (nwg >> 3) + (bid >> 3);
}

// ---------------- prep kernels ----------------
__global__ void k_cast_hs(const float* __restrict__ in, u16* __restrict__ out){
  size_t i = (size_t)blockIdx.x * 256 + threadIdx.x;   // 8 elems / thread
  const f32x4* p = (const f32x4*)in;
  f32x4 a = p[i*2], b = p[i*2+1];
  u16x8 o;
  o[0]=f2bf(a[0]); o[1]=f2bf(a[1]); o[2]=f2bf(a[2]); o[3]=f2bf(a[3]);
  o[4]=f2bf(b[0]); o[5]=f2bf(b[1]); o[6]=f2bf(b[2]); o[7]=f2bf(b[3]);
  ((u16x8*)out)[i] = o;
}

// fp32 [2048][2048] -> bf16 transposed [2048][2048] (out[n][k] = in[k][n])
__global__ void k_transpose_w(const float* __restrict__ in, u16* __restrict__ out){
  __shared__ float t[64][65];
  const int tid = threadIdx.x;
  const int k0 = blockIdx.x * 64, n0 = blockIdx.y * 64;
#pragma unroll
  for (int it = 0; it < 4; ++it){
    int slot = it*256 + tid;                 // 1024 float4 slots
    int r = slot >> 4, c = (slot & 15) * 4;
    f32x4 v = *(const f32x4*)&in[(size_t)(k0+r)*DMODEL + n0 + c];
    t[r][c] = v[0]; t[r][c+1] = v[1]; t[r][c+2] = v[2]; t[r][c+3] = v[3];
  }
  __syncthreads();
#pragma unroll
  for (int it = 0; it < 2; ++it){
    int slot = it*256 + tid;                 // 64 n-rows x 8 chunks
    int r = slot >> 3, c = (slot & 7) * 8;
    u16x8 o;
#pragma unroll
    for (int j = 0; j < 8; ++j) o[j] = f2bf(t[c+j][r]);
    *(u16x8*)&out[(size_t)(n0+r)*DMODEL + k0 + c] = o;
  }
}

__global__ void k_tables(const float* __restrict__ fr, float* __restrict__ cn,
                         float* __restrict__ sn){
  int i = blockIdx.x*256 + threadIdx.x;      // S*128 elements
  float f = fr[i];
  cn[i] = cosf(f); sn[i] = sinf(f);
}

// ---------------- shared GEMM mainloop:  C(128x128) = A[M][2048] * Bt[N][2048]^T
// (single-buffer, two syncthreads per K-step, 16x16x32 core)
__device__ __forceinline__ void gemm_loop(const u16* __restrict__ A,
                                          const u16* __restrict__ Bt,
                                          int m0, int n0,
                                          u16* Asm, u16* Bsm,
                                          f32x4 (&acc)[4][4], int lane, int wid){
  const int wr = wid >> 1, wc = wid & 1;
#pragma unroll 1
  for (int kt = 0; kt < DMODEL/64; ++kt){
#pragma unroll
    for (int it = 0; it < 4; ++it){
      int slot = it*256 + wid*64 + lane;     // 1024 chunks per tile
      int row = slot >> 3, cs = slot & 7;
      int ci = cs ^ (row & 7);
      gload16(A  + (size_t)(m0+row)*DMODEL + kt*64 + ci*8, Asm + (size_t)(it*256 + wid*64)*8);
      gload16(Bt + (size_t)(n0+row)*DMODEL + kt*64 + ci*8, Bsm + (size_t)(it*256 + wid*64)*8);
    }
    __syncthreads();
#pragma unroll
    for (int ks = 0; ks < 2; ++ks){
      bf16x8 af[4], bfv[4];
#pragma unroll
      for (int mt = 0; mt < 4; ++mt){
        int row = wr*64 + mt*16 + (lane & 15);
        int cs = (ks*4 + (lane >> 4)) ^ (row & 7);
        af[mt] = *(const bf16x8*)(Asm + ((size_t)row*8 + cs)*8);
      }
#pragma unroll
      for (int nt = 0; nt < 4; ++nt){
        int row = wc*64 + nt*16 + (lane & 15);
        int cs = (ks*4 + (lane >> 4)) ^ (row & 7);
        bfv[nt] = *(const bf16x8*)(Bsm + ((size_t)row*8 + cs)*8);
      }
#pragma unroll
      for (int mt = 0; mt < 4; ++mt)
#pragma unroll
        for (int nt = 0; nt < 4; ++nt)
          acc[mt][nt] = __builtin_amdgcn_mfma_f32_16x16x32_bf16(af[mt], bfv[nt], acc[mt][nt], 0, 0, 0);
    }
    __syncthreads();
  }
}

// QKV projection GEMM. N=6144 = [q 2048 | k 2048 | v 2048].
__global__ __launch_bounds__(256, 2)
void k_gemm_qkv(const u16* __restrict__ A, const u16* __restrict__ Bt,
                u16* __restrict__ qkp, u16* __restrict__ vt){
  __shared__ u16 Asm[128*64];
  __shared__ u16 Bsm[128*64];
  const int lane = threadIdx.x & 63, wid = threadIdx.x >> 6;
  const int m0 = blockIdx.x * 128, n0 = blockIdx.y * 128;
  f32x4 acc[4][4] = {};
  gemm_loop(A, Bt, m0, n0, Asm, Bsm, acc, lane, wid);
  const int wr = wid >> 1, wc = wid & 1;
  if (n0 < 2*DMODEL){
#pragma unroll
    for (int mt = 0; mt < 4; ++mt)
#pragma unroll
      for (int nt = 0; nt < 4; ++nt){
        int col = n0 + wc*64 + nt*16 + (lane & 15);
#pragma unroll
        for (int r = 0; r < 4; ++r){
          int row = m0 + wr*64 + mt*16 + (lane >> 4)*4 + r;
          qkp[(size_t)row*4096 + col] = f2bf(acc[mt][nt][r]);
        }
      }
  } else {
    const int hh = (n0 - 2*DMODEL) >> 7;     // head
    const int b  = m0 >> 12;                 // row / S_LEN
#pragma unroll
    for (int mt = 0; mt < 4; ++mt)
#pragma unroll
      for (int nt = 0; nt < 4; ++nt){
        u16x4 pk;
#pragma unroll
        for (int r = 0; r < 4; ++r) pk[r] = f2bf(acc[mt][nt][r]);
        int d  = wc*64 + nt*16 + (lane & 15);
        int s_ = (m0 & (S_LEN-1)) + wr*64 + mt*16 + (lane >> 4)*4;
        *(u16x4*)&vt[(((size_t)b*NHEAD + hh)*HDIM + d)*S_LEN + s_] = pk;
      }
  }
}

// per-head RMSNorm + RoPE; Q scaled by log2e/sqrt(128); layout [b][h][s][d]
__global__ __launch_bounds__(256)
void k_qk_post(const u16* __restrict__ qkp, const float* __restrict__ cn,
               const float* __restrict__ sn, const float* __restrict__ wqn,
               const float* __restrict__ wkn, u16* __restrict__ Qo, u16* __restrict__ Ko){
  const int lane = threadIdx.x & 63, wid = threadIdx.x >> 6;
  const int gw = blockIdx.x*4 + wid;     // (b*S+s)*16 + h
  const int row = gw >> 4;
  const int h  = gw & 15;
  const int s_ = row & (S_LEN-1);
  const int b  = row >> 12;
  const float c1 = cn[s_*HDIM + lane],      c2 = cn[s_*HDIM + 64 + lane];
  const float t1 = sn[s_*HDIM + lane],      t2 = sn[s_*HDIM + 64 + lane];
  const size_t ob = (((size_t)b*NHEAD + h)*S_LEN + s_)*HDIM;
  {
    const u16* p = qkp + (size_t)row*4096 + h*HDIM;
    float x1 = bf2f(p[lane]), x2 = bf2f(p[lane+64]);
    float ss = x1*x1 + x2*x2;
#pragma unroll
    for (int m = 1; m < 64; m <<= 1) ss += __shfl_xor(ss, m);
    float rn = rsqrtf(ss*(1.0f/128.0f) + 1e-5f);
    x1 *= rn * wqn[lane]; x2 *= rn * wqn[lane+64];
    const float qs = 0.12751743f;          // log2(e)/sqrt(128), folded softmax scale
    Qo[ob + lane]      = f2bf((x1*c1 - x2*t1) * qs);
    Qo[ob + 64 + lane] = f2bf((x2*c2 + x1*t2) * qs);
  }
  {
    const u16* p = qkp + (size_t)row*4096 + 2048 + h*HDIM;
    float x1 = bf2f(p[lane]), x2 = bf2f(p[lane+64]);
    float ss = x1*x1 + x2*x2;
#pragma unroll
    for (int m = 1; m < 64; m <<= 1) ss += __shfl_xor(ss, m);
    float rn = rsqrtf(ss*(1.0f/128.0f) + 1e-5f);
    x1 *= rn * wkn[lane]; x2 *= rn * wkn[lane+64];
    Ko[ob + lane]      = f2bf(x1*c1 - x2*t1);
    Ko[ob + 64 + lane] = f2bf(x2*c2 + x1*t2);
  }
}

// ---------------- attention: swapped-QK^T 32x32, in-register softmax ----------------
// 4 waves; wave w owns q rows [q0+32w, +32). Counted-vmcnt double-buffer,
// raw barriers, setprio, XCD-chunked block map (K/V panels L2-resident).
__device__ __forceinline__ void stage_kv(const u16* __restrict__ Kg,
                                         const u16* __restrict__ Vt,
                                         size_t base, int kb,
                                         u16* Ksm, u16* Vsm, int lane, int wid){
#pragma unroll
  for (int it = 0; it < 4; ++it){
    int slot = it*256 + wid*64 + lane;       // 1024 chunks per tile
    { int row = slot >> 4, cs = slot & 15, ci = cs ^ (row & 7);
      gload16(Kg + base + (size_t)(kb*64 + row)*HDIM + ci*8, Ksm + (size_t)(it*256 + wid*64)*8); }
    { int row = slot >> 3, cs = slot & 7,  ci = cs ^ (row & 7);
      gload16(Vt + base + (size_t)row*S_LEN + kb*64 + ci*8,  Vsm + (size_t)(it*256 + wid*64)*8); }
  }
}

__global__ __launch_bounds__(256, 2)
void k_attn(const u16* __restrict__ Q, const u16* __restrict__ Kg,
            const u16* __restrict__ Vt, u16* __restrict__ Og){
  __shared__ u16 Ksm[2][64*128];           // [key][d], 16 chunks/row, ci = cs^(row&7)
  __shared__ u16 Vsm[2][128*64];           // [d][key],  8 chunks/row, ci = cs^(row&7)
  const int lane = threadIdx.x & 63, wid = threadIdx.x >> 6;
  const int col = lane & 31, hi = lane >> 5;
  const int t  = xcd_chunk(blockIdx.x, 1024);    // each XCD: 4 bh -> K/V L2-resident
  const int bh = t >> 5;
  const int q0 = (t & 31) * 128;
  const int b = bh >> 4, h = bh & 15;
  const size_t base = (size_t)bh * S_LEN * HDIM;
  const int qw = q0 + wid*32;

  stage_kv(Kg, Vt, base, 0, Ksm[0], Vsm[0], lane, wid);   // prologue: tile 0 (8 ops)

  // Q fragments (B-operand): qb[ks] = Q[qw+col][ks*16 + hi*8 .. +8]
  bf16x8 qb[8];
  {
    const u16* qp = Q + base + (size_t)(qw + col)*HDIM + hi*8;
#pragma unroll
    for (int ks = 0; ks < 8; ++ks) qb[ks] = *(const bf16x8*)(qp + ks*16);
  }
  f32x16 acc[4] = {};                      // O[q=crow(r,hi)][d=dt*32+col]
  float lsum = 0.f;                        // half-key-set softmax partial for q=col
  int cur = 0;

#pragma unroll 1
  for (int kb = 0; kb < S_LEN/64; ++kb){
    // ---- issue NEXT tile's loads; wait only for OWN tile-kb loads ----
    if (kb + 1 < S_LEN/64){
      stage_kv(Kg, Vt, base, kb + 1, Ksm[cur ^ 1], Vsm[cur ^ 1], lane, wid);
      asm volatile("s_waitcnt vmcnt(8)" ::: "memory");
    } else {
      asm volatile("s_waitcnt vmcnt(0)" ::: "memory");
    }
    __builtin_amdgcn_s_barrier();          // all waves' tile-kb loads resident
    asm volatile("" ::: "memory");
    const u16* Ks = Ksm[cur];
    const u16* Vs = Vsm[cur];

    // ---- S^T = K * Q^T : A=K (keys x d), B=Q (d x q) ----
    f32x16 s0 = {}, s1 = {};
    __builtin_amdgcn_s_setprio(1);
#pragma unroll
    for (int ks = 0; ks < 8; ++ks){
      int slot = (ks*2 + hi);
      int r0 = col;            // keys 0..31
      bf16x8 kf0 = *(const bf16x8*)(Ks + (size_t)r0*128 + (size_t)(slot ^ (r0 & 7))*8);
      s0 = __builtin_amdgcn_mfma_f32_32x32x16_bf16(kf0, qb[ks], s0, 0, 0, 0);
      int r1 = col + 32;       // keys 32..63
      bf16x8 kf1 = *(const bf16x8*)(Ks + (size_t)r1*128 + (size_t)(slot ^ (r1 & 7))*8);
      s1 = __builtin_amdgcn_mfma_f32_32x32x16_bf16(kf1, qb[ks], s1, 0, 0, 0);
    }
    __builtin_amdgcn_s_setprio(0);

    // ---- P = exp2(S); lane holds P[key=(r&3)+4*hi+8*(r>>2)+32*grp][q=col] ----
    float p0[16], p1[16];
#pragma unroll
    for (int r = 0; r < 16; ++r){
      p0[r] = __builtin_amdgcn_exp2f(s0[r]);
      p1[r] = __builtin_amdgcn_exp2f(s1[r]);
      lsum += p0[r] + p1[r];
    }
    // pack adjacent-r pairs: cw[j] = bf16(p[2j]) | bf16(p[2j+1])<<16
    u32 cw0[8], cw1[8];
#pragma unroll
    for (int j = 0; j < 8; ++j){
      cw0[j] = cvtpk(p0[2*j], p0[2*j+1]);
      cw1[j] = cvtpk(p1[2*j], p1[2*j+1]);
    }
    // redistribute so pa[ks][e] = P[q=col][key = ks*16 + hi*8 + e].
    bf16x8 pa[4];
#pragma unroll
    for (int ks = 0; ks < 4; ++ks){
      const u32* cw = (ks < 2) ? cw0 : cw1;
      const int c4 = (ks & 1) * 4;
      u32 n0 = hi ? cw[c4+2] : cw[c4+0];   // what this lane consumes natively
      u32 n1 = hi ? cw[c4+3] : cw[c4+1];
      u32 s0w = hi ? cw[c4+0] : cw[c4+2];  // what the PARTNER's hi needs
      u32 s1w = hi ? cw[c4+1] : cw[c4+3];
      u32 f0 = __shfl_xor((int)s0w, 32);
      u32 f1 = __shfl_xor((int)s1w, 32);
      u32x4 w;
      w[0] = hi ? f0 : n0;                 // words 0,1 sourced from half 0
      w[1] = hi ? f1 : n1;
      w[2] = hi ? n0 : f0;                 // words 2,3 sourced from half 1
      w[3] = hi ? n1 : f1;
      pa[ks] = __builtin_bit_cast(bf16x8, w);
    }

    // ---- O += P * V : A=P (q x key), B=V (key x d) ----
    __builtin_amdgcn_s_setprio(1);
#pragma unroll
    for (int dt = 0; dt < 4; ++dt){
      int row = dt*32 + col;
      const u16* vb = Vs + (size_t)row*64;
      int sw = row & 7;
#pragma unroll
      for (int ks = 0; ks < 4; ++ks){
        bf16x8 vf = *(const bf16x8*)(vb + (size_t)((ks*2 + hi) ^ sw)*8);
        acc[dt] = __builtin_amdgcn_mfma_f32_32x32x16_bf16(pa[ks], vf, acc[dt], 0, 0, 0);
      }
    }
    __builtin_amdgcn_s_setprio(0);
    __builtin_amdgcn_s_barrier();          // reads retired; buffer reusable
    asm volatile("" ::: "memory");
    cur ^= 1;
  }

  // ---- epilogue: normalize rows and store bf16 ----
  float tot = lsum + __shfl_xor(lsum, 32);           // full row sum for q=col
  float inv[16];
#pragma unroll
  for (int r = 0; r < 16; ++r){
    int qr = (r & 3) + 4*hi + 8*(r >> 2);            // q-within-32 of acc elem r
    inv[r] = 1.0f / __shfl(tot, qr);
  }
  const size_t orow0 = (size_t)b*S_LEN + q0 + wid*32;
#pragma unroll
  for (int dt = 0; dt < 4; ++dt){
    int d = h*HDIM + dt*32 + col;
#pragma unroll
    for (int r = 0; r < 16; ++r){
      int qr = (r & 3) + 4*hi + 8*(r >> 2);
      Og[(orow0 + qr)*DMODEL + d] = f2bf(acc[dt][r] * inv[r]);
    }
  }
}

// out = attn[8192][2048] @ w_out + b_out  (fp32 out)
__global__ __launch_bounds__(256, 2)
void k_gemm_out(const u16* __restrict__ A, const u16* __restrict__ Bt,
                const float* __restrict__ bias, float* __restrict__ out){
  __shared__ u16 Asm[128*64];
  __shared__ u16 Bsm[128*64];
  const int lane = threadIdx.x & 63, wid = threadIdx.x >> 6;
  const int m0 = blockIdx.x * 128, n0 = blockIdx.y * 128;
  f32x4 acc[4][4] = {};
  gemm_loop(A, Bt, m0, n0, Asm, Bsm, acc, lane, wid);
  const int wr = wid >> 1, wc = wid & 1;
  float bv[4];
#pragma unroll
  for (int nt = 0; nt < 4; ++nt) bv[nt] = bias[n0 + wc*64 + nt*16 + (lane & 15)];
#pragma unroll
  for (int mt = 0; mt < 4; ++mt)
#pragma unroll
    for (int nt = 0; nt < 4; ++nt){
      int col = n0 + wc*64 + nt*16 + (lane & 15);
#pragma unroll
      for (int r = 0; r < 4; ++r){
        int row = m0 + wr*64 + mt*16 + (lane >> 4)*4 + r;
        out[(size_t)row*DMODEL + col] = acc[mt][nt][r] + bv[nt];
      }
    }
}

extern "C" void kernel_launch(void* const* d_in, const int* in_sizes, int n_in,
                              void* d_out, int out_size, void* d_ws, size_t ws_size,
                              hipStream_t stream){
  const float* hs    = (const float*)d_in[0];
  const float* freqs = (const float*)d_in[1];
  const float* wq    = (const float*)d_in[2];
  const float* wk    = (const float*)d_in[3];
  const float* wv    = (const float*)d_in[4];
  const float* nqw   = (const float*)d_in[5];
  const float* nkw   = (const float*)d_in[6];
  const float* wo    = (const float*)d_in[7];
  const float* bo    = (const float*)d_in[8];
  float* out = (float*)d_out;

  char* ws = (char*)d_ws;
  u16*   hs_bf = (u16*)(ws + 0);              // 33,554,432  (later reused as Q)
  u16*   wqkvT = (u16*)(ws + 33554432);       // 25,165,824
  u16*   woutT = (u16*)(ws + 58720256);       //  8,388,608
  float* cosn  = (float*)(ws + 67108864);     //  2,097,152
  float* sinn  = (float*)(ws + 69206016);     //  2,097,152
  u16*   qkp   = (u16*)(ws + 71303168);       // 67,108,864  (later reused as attn out)
  u16*   vt    = (u16*)(ws + 138412032);      // 33,554,432
  u16*   kbuf  = (u16*)(ws + 171966464);      // 33,554,432
  if (ws_size < 205520896ULL) return;         // need ~196 MiB of scratch
  u16* qbuf = hs_bf;                          // alias: hs dead after QKV GEMM
  u16* attn = qkp;                            // alias: qk-proj dead after qk_post

  k_cast_hs    <<<8192, 256, 0, stream>>>(hs, hs_bf);
  k_transpose_w<<<dim3(32,32), 256, 0, stream>>>(wq, wqkvT);
  k_transpose_w<<<dim3(32,32), 256, 0, stream>>>(wk, wqkvT + (size_t)DMODEL*DMODEL);
  k_transpose_w<<<dim3(32,32), 256, 0, stream>>>(wv, wqkvT + (size_t)2*DMODEL*DMODEL);
  k_transpose_w<<<dim3(32,32), 256, 0, stream>>>(wo, woutT);
  k_tables     <<<2048, 256, 0, stream>>>(freqs, cosn, sinn);
  k_gemm_qkv   <<<dim3(64,48), 256, 0, stream>>>(hs_bf, wqkvT, qkp, vt);
  k_qk_post    <<<32768, 256, 0, stream>>>(qkp, cosn, sinn, nqw, nkw, qbuf, kbuf);
  k_attn       <<<1024, 256, 0, stream>>>(qbuf, kbuf, vt, attn);
  k_gemm_out   <<<dim3(64,16), 256, 0, stream>>>(attn, woutT, bo, out);
}